// Round 7
// baseline (187.079 us; speedup 1.0000x reference)
//
#include <hip/hip_runtime.h>
#include <stdint.h>

// DCNv2 forward, MI355X — fused-sampling pipeline:
//  K0 prep_weights : W -> WB bf16 [kk/8][o][8]; p_weight -> PWs bf16 (N=32 pad);
//                    zeroes the OOB zeropage (d_ws is poisoned every launch).
//  K1 transpose_x  : x NCHW fp32 -> xt NHWC bf16 (halves sampling bytes; values
//                    are bf16-rounded before MFMA anyway).
//  K2 offset_conv_sk : split-K (S=8) implicit-im2col bf16 MFMA conv, BM=64,
//                      XCD-swizzled; A staged by global_load_lds from bf16 xt
//                      (OOB rows -> zeropage). fp32 partials Pbuf[s][m][32].
//  K3 finalize_taps: reduce partials + bias + sigmoid; precompute per-(m,tap)
//                    clamped corner element-offsets (int4) and mask*valid-folded
//                    bilinear weights (float4).
//  K4 dcn_fused    : BM=64 x BN=256, 72 BK32 iters. A tile (64x256 bf16, 32KB)
//                    sampled in-kernel: each wave samples its 16 rows into regs
//                    (2 rows/iter) and flushes at tap boundary (+1 barrier/tap).
//                    B ping-pong dbuf 2x16KB via global_load_lds. LDS = 64KB.
//                    Amat (75.5MB) eliminated. Epilogue +bias -> NCHW fp32.
// Workspace ~31 MB of 256 MiB.

#define CIN 256
#define COUT 256
#define HWS 4096      // H*W
#define MTOT 16384    // B*H*W
#define KTOT 2304     // CIN*9
#define SPLITK 8

typedef __attribute__((ext_vector_type(8))) short bf16x8;
typedef __attribute__((ext_vector_type(4))) float f32x4;

__device__ __forceinline__ unsigned short f2bf(float f) {
  unsigned int u = __float_as_uint(f);
  unsigned int r = (u + 0x7fffu + ((u >> 16) & 1u)) >> 16;
  return (unsigned short)r;
}
__device__ __forceinline__ float bf2f(unsigned short u) {
  return __uint_as_float(((unsigned int)u) << 16);
}

__device__ __forceinline__ void gload_lds16(const void* g, void* l) {
  __builtin_amdgcn_global_load_lds((const __attribute__((address_space(1))) void*)g,
                                   (__attribute__((address_space(3))) void*)l, 16, 0, 0);
}

// ---------------- K0: weight prep + zeropage ----------------
__global__ __launch_bounds__(256) void prep_weights(const float* __restrict__ w,
                                                    const float* __restrict__ pw,
                                                    unsigned short* __restrict__ WB,
                                                    unsigned short* __restrict__ PWs,
                                                    unsigned short* __restrict__ zerop) {
  int idx = blockIdx.x * 256 + threadIdx.x;
  if (idx < 512) {  // 8 KB zeropage
    *(uint4*)(zerop + idx * 8) = make_uint4(0, 0, 0, 0);
  }
  if (idx < KTOT * COUT) {
    int f = idx;
    int t_ = f & 7;
    int rest = f >> 3;
    int o = rest & 255;
    int kk = (rest >> 8) * 8 + t_;
    int k = kk >> 8, c = kk & 255;
    WB[f] = f2bf(w[o * KTOT + c * 9 + k]);
  } else {
    int f2 = idx - KTOT * COUT;   // < 2304*32
    int t_ = f2 & 7;
    int rest = f2 >> 3;
    int j = rest & 31;
    int kk = (rest >> 5) * 8 + t_;
    int k = kk >> 8, c = kk & 255;
    float v = (j < 27) ? pw[j * KTOT + c * 9 + k] : 0.0f;
    PWs[f2] = f2bf(v);
  }
}

// ---------------- K1: NCHW fp32 -> NHWC bf16 transpose ----------------
__global__ __launch_bounds__(256) void transpose_x(const float* __restrict__ x,
                                                   unsigned short* __restrict__ xt) {
  __shared__ float tile[32][33];
  int b = blockIdx.z;
  int hw0 = blockIdx.x * 32;
  int c0 = blockIdx.y * 32;
  int tx = threadIdx.x, ty = threadIdx.y;
  for (int i = ty; i < 32; i += 8)
    tile[i][tx] = x[(size_t)(b * CIN + c0 + i) * HWS + hw0 + tx];
  __syncthreads();
  for (int r = ty; r < 32; r += 8)
    xt[(size_t)(b * HWS + hw0 + r) * CIN + c0 + tx] = f2bf(tile[tx][r]);
}

// ---------------- K2: offset conv, split-K, BM=64, bf16-xt staging ----------------
__global__ __launch_bounds__(256) void offset_conv_sk(const unsigned short* __restrict__ xt,
                                                      const unsigned short* __restrict__ PWs,
                                                      const unsigned short* __restrict__ zerop,
                                                      float* __restrict__ Pbuf) {
  __shared__ unsigned short Al[64 * 32];   // 4 KB
  __shared__ unsigned short Bl[1024];      // 2 KB
  int tid = threadIdx.x;
  int lane = tid & 63, wv = tid >> 6;
  int mt = (blockIdx.x & 7) * 32 + (blockIdx.x >> 3);   // XCD swizzle
  int m0 = mt * 64;
  int s = blockIdx.y;
  int b = m0 >> 12;
  int hw0 = m0 & 4095;
  f32x4 acc[2] = {};

  for (int tt = 0; tt < 72 / SPLITK; ++tt) {
    int t = s * (72 / SPLITK) + tt;
    int k = t >> 3, c0 = (t & 7) * 32;
    int dyk = k / 3 - 1;
    int dxk = k % 3 - 1;
    __syncthreads();
    // stage B: 2 KB = 128 x 16B chunks (waves 0,1)
    if (tid < 128)
      gload_lds16(PWs + (size_t)t * 1024 + tid * 8, &Bl[tid * 8]);
    // stage A: 64 rows x 32 ch bf16 = 4 KB; thread -> one 16B chunk (8 ch)
    {
      int r = tid >> 2;
      int hw = hw0 + r;
      int h = hw >> 6, wwp = hw & 63;
      int y = h + dyk, xx = wwp + dxk;
      bool valid = ((unsigned)y < 64u) && ((unsigned)xx < 64u);
      const unsigned short* src = valid
          ? xt + ((size_t)((b << 12) + (y << 6) + xx) << 8) + c0 + (tid & 3) * 8
          : zerop;
      gload_lds16(src, &Al[tid * 8]);
    }
    __syncthreads();
    int row = lane & 15, quad = lane >> 4;
    bf16x8 af = *(const bf16x8*)&Al[(wv * 16 + row) * 32 + quad * 8];
    for (int j = 0; j < 2; ++j) {
      bf16x8 bfr = *(const bf16x8*)&Bl[(quad * 32 + j * 16 + row) * 8];
      acc[j] = __builtin_amdgcn_mfma_f32_16x16x32_bf16(af, bfr, acc[j], 0, 0, 0);
    }
  }

  int row = lane & 15, quad = lane >> 4;
  for (int j = 0; j < 2; ++j) {
    int n = j * 16 + row;
    for (int r_ = 0; r_ < 4; ++r_) {
      int m = m0 + wv * 16 + quad * 4 + r_;
      Pbuf[((size_t)s * MTOT + m) * 32 + n] = acc[j][r_];
    }
  }
}

// ---------------- K3: finalize taps: partials -> corner offsets + weights ----------------
__global__ __launch_bounds__(256) void finalize_taps(const float* __restrict__ Pbuf,
                                                     const float* __restrict__ p_bias,
                                                     int4* __restrict__ descI,
                                                     float4* __restrict__ descW) {
  int reg = blockIdx.x & 7;                 // region == XCD (matches K2 producer)
  int tr = (blockIdx.x >> 3) * 256 + threadIdx.x;   // < 18432
  int ml = tr / 9;
  int k = tr - ml * 9;
  int m = reg * 2048 + ml;

  float dy = p_bias[2 * k];
  float dx = p_bias[2 * k + 1];
  float mv = p_bias[18 + k];
#pragma unroll
  for (int s = 0; s < SPLITK; ++s) {
    const float* p = Pbuf + ((size_t)s * MTOT + m) * 32;
    dy += p[2 * k];
    dx += p[2 * k + 1];
    mv += p[18 + k];
  }
  float mk = 1.0f / (1.0f + __expf(-mv));

  int hw = m & 4095, h = hw >> 6, ww = hw & 63;
  float py = (float)(h - 1 + k / 3) + dy;
  float px = (float)(ww - 1 + k % 3) + dx;
  float y0f = floorf(py), x0f = floorf(px);
  float ay = py - y0f, ax = px - x0f;
  int y0 = (int)y0f, x0 = (int)x0f;

  float w00 = (1.f - ay) * (1.f - ax) * mk;
  float w01 = (1.f - ay) * ax * mk;
  float w10 = ay * (1.f - ax) * mk;
  float w11 = ay * ax * mk;

  float vy0 = ((unsigned)y0 < 64u) ? 1.f : 0.f;
  float vy1 = ((unsigned)(y0 + 1) < 64u) ? 1.f : 0.f;
  float vx0 = ((unsigned)x0 < 64u) ? 1.f : 0.f;
  float vx1 = ((unsigned)(x0 + 1) < 64u) ? 1.f : 0.f;
  w00 *= vy0 * vx0; w01 *= vy0 * vx1; w10 *= vy1 * vx0; w11 *= vy1 * vx1;

  int yc0 = min(max(y0, 0), 63), yc1 = min(max(y0 + 1, 0), 63);
  int xc0 = min(max(x0, 0), 63), xc1 = min(max(x0 + 1, 0), 63);

  int di = m * 9 + k;
  descI[di] = make_int4((yc0 * 64 + xc0) * 256, (yc0 * 64 + xc1) * 256,
                        (yc1 * 64 + xc0) * 256, (yc1 * 64 + xc1) * 256);
  descW[di] = make_float4(w00, w01, w10, w11);
}

// ---------------- K4: fused sample + GEMM, BM=64 x BN=256, BK=32 ----------------
__global__ __launch_bounds__(256, 1) void dcn_fused(const unsigned short* __restrict__ xt,
                                                    const unsigned short* __restrict__ WB,
                                                    const int4* __restrict__ descI,
                                                    const float4* __restrict__ descW,
                                                    const float* __restrict__ bias,
                                                    float* __restrict__ out) {
  __shared__ unsigned short Asm[64 * 256];       // 32 KB, current tap's A tile
  __shared__ unsigned short Bsm[2][4 * 256 * 8]; // 2 x 16 KB ping-pong
  int tid = threadIdx.x;
  int lane = tid & 63, wv = tid >> 6;
  int reg = blockIdx.x & 7;                      // XCD region
  int m0 = reg * 2048 + (blockIdx.x >> 3) * 64;
  int b = m0 >> 12, hw0 = m0 & 4095;
  const unsigned short* xtb = xt + (((size_t)b << 12) << 8);
  int row = lane & 15, quad = lane >> 4;
  f32x4 acc[4][4] = {};
  uint2 sreg[16];

  // stage one BK32 B chunk (16 KB) into buffer bufi
  auto stageB = [&](int it, int bufi) {
#pragma unroll
    for (int p = 0; p < 4; ++p) {
      int li = p * 256 + tid;
      int kb8 = li >> 8, col = li & 255;
      gload_lds16(WB + ((size_t)(it * 4 + kb8) * 256 + col) * 8, &Bsm[bufi][li * 8]);
    }
  };
  // sample one row (this wave's local row r) of tap k -> packed 4 bf16
  auto sampleRow = [&](int k, int r) -> uint2 {
    int di = (m0 + wv * 16 + r) * 9 + k;
    int4 o4 = descI[di];
    float4 w4 = descW[di];
    ushort4 t00 = *(const ushort4*)(xtb + o4.x + 4 * lane);
    ushort4 t01 = *(const ushort4*)(xtb + o4.y + 4 * lane);
    ushort4 t10 = *(const ushort4*)(xtb + o4.z + 4 * lane);
    ushort4 t11 = *(const ushort4*)(xtb + o4.w + 4 * lane);
    float r0 = w4.x * bf2f(t00.x) + w4.y * bf2f(t01.x) + w4.z * bf2f(t10.x) + w4.w * bf2f(t11.x);
    float r1 = w4.x * bf2f(t00.y) + w4.y * bf2f(t01.y) + w4.z * bf2f(t10.y) + w4.w * bf2f(t11.y);
    float r2 = w4.x * bf2f(t00.z) + w4.y * bf2f(t01.z) + w4.z * bf2f(t10.z) + w4.w * bf2f(t11.z);
    float r3 = w4.x * bf2f(t00.w) + w4.y * bf2f(t01.w) + w4.z * bf2f(t10.w) + w4.w * bf2f(t11.w);
    uint2 o;
    o.x = (unsigned)f2bf(r0) | ((unsigned)f2bf(r1) << 16);
    o.y = (unsigned)f2bf(r2) | ((unsigned)f2bf(r3) << 16);
    return o;
  };
  auto writeRow = [&](int r, uint2 v) {
    *(uint2*)&Asm[(wv * 16 + r) * 256 + 4 * lane] = v;
  };

  // prologue: B chunk 0 + tap 0 A tile
  stageB(0, 0);
#pragma unroll
  for (int r = 0; r < 16; ++r) writeRow(r, sampleRow(0, r));
  __syncthreads();

  for (int k = 0; k < 9; ++k) {
#pragma unroll
    for (int q = 0; q < 8; ++q) {
      int it = k * 8 + q;
      int bufi = it & 1;
      if (it < 71) stageB(it + 1, bufi ^ 1);
      if (k < 8) {
        sreg[2 * q]     = sampleRow(k + 1, 2 * q);
        sreg[2 * q + 1] = sampleRow(k + 1, 2 * q + 1);
      }
      bf16x8 af[4], bfr[4];
#pragma unroll
      for (int i = 0; i < 4; ++i)
        af[i] = *(const bf16x8*)&Asm[(i * 16 + row) * 256 + q * 32 + quad * 8];
#pragma unroll
      for (int j = 0; j < 4; ++j)
        bfr[j] = *(const bf16x8*)&Bsm[bufi][(quad * 256 + wv * 64 + j * 16 + row) * 8];
#pragma unroll
      for (int i = 0; i < 4; ++i)
#pragma unroll
        for (int j = 0; j < 4; ++j)
          acc[i][j] = __builtin_amdgcn_mfma_f32_16x16x32_bf16(af[i], bfr[j], acc[i][j], 0, 0, 0);
      __syncthreads();
    }
    if (k < 8) {   // flush tap k+1 A tile (reads of tap k all completed at barrier)
#pragma unroll
      for (int r = 0; r < 16; ++r) writeRow(r, sreg[r]);
      __syncthreads();
    }
  }

  // epilogue: +bias, NCHW fp32
#pragma unroll
  for (int j = 0; j < 4; ++j) {
    int o = wv * 64 + j * 16 + row;
    float bo = bias[o];
#pragma unroll
    for (int i = 0; i < 4; ++i) {
      int hw = hw0 + i * 16 + quad * 4;
      float4 v;
      v.x = acc[i][j][0] + bo;
      v.y = acc[i][j][1] + bo;
      v.z = acc[i][j][2] + bo;
      v.w = acc[i][j][3] + bo;
      *(float4*)(out + (((size_t)(b * COUT + o)) << 12) + hw) = v;
    }
  }
}

// ---------------- launch ----------------
extern "C" void kernel_launch(void* const* d_in, const int* in_sizes, int n_in,
                              void* d_out, int out_size, void* d_ws, size_t ws_size,
                              hipStream_t stream) {
  const float* x        = (const float*)d_in[0];
  const float* weight   = (const float*)d_in[1];
  const float* bias     = (const float*)d_in[2];
  const float* p_weight = (const float*)d_in[3];
  const float* p_bias   = (const float*)d_in[4];
  float* out = (float*)d_out;
  char* ws = (char*)d_ws;

  // workspace layout (bytes); total ~31.2 MB
  const size_t OFF_XT   = 0;                          //  8,388,608  bf16 NHWC x
  const size_t OFF_WB   = OFF_XT + 8388608;           //  1,179,648  bf16
  const size_t OFF_PW   = OFF_WB + 1179648;           //    147,456  bf16
  const size_t OFF_P    = OFF_PW + 147456;            // 16,777,216  fp32 partials
  const size_t OFF_DI   = OFF_P + 16777216;           //  2,359,296  int4 desc
  const size_t OFF_DW   = OFF_DI + 2359296;           //  2,359,296  float4 desc
  const size_t OFF_ZP   = OFF_DW + 2359296;           //      8,192  zeropage

  unsigned short* xt   = (unsigned short*)(ws + OFF_XT);
  unsigned short* WB   = (unsigned short*)(ws + OFF_WB);
  unsigned short* PWs  = (unsigned short*)(ws + OFF_PW);
  float* Pbuf          = (float*)(ws + OFF_P);
  int4* descI          = (int4*)(ws + OFF_DI);
  float4* descW        = (float4*)(ws + OFF_DW);
  unsigned short* zerop = (unsigned short*)(ws + OFF_ZP);

  prep_weights<<<(KTOT * COUT + KTOT * 32) / 256, 256, 0, stream>>>(weight, p_weight, WB, PWs, zerop);
  transpose_x<<<dim3(128, 8, 4), dim3(32, 8), 0, stream>>>(x, xt);
  offset_conv_sk<<<dim3(MTOT / 64, SPLITK), 256, 0, stream>>>(xt, PWs, zerop, Pbuf);
  finalize_taps<<<(MTOT * 9) / 256, 256, 0, stream>>>(Pbuf, p_bias, descI, descW);
  dcn_fused<<<MTOT / 64, 256, 0, stream>>>(xt, WB, descI, descW, bias, out);
}

// Round 8
// 185.285 us; speedup vs baseline: 1.0097x; 1.0097x over previous
//
#include <hip/hip_runtime.h>
#include <stdint.h>

// DCNv2 forward, MI355X — fused-sampling pipeline (R7 fix):
//  K0 prep_weights : W -> WB bf16 [kk/8][o][8]; p_weight -> PWs bf16 (N=32 pad);
//                    zeroes the OOB zeropage.
//  K1 transpose_x  : x NCHW fp32 -> xt NHWC bf16.
//  K2 offset_conv_sk : split-K (S=8) implicit-im2col bf16 MFMA conv, BM=64,
//                      XCD-swizzled; A staged via global_load_lds from bf16 xt.
//  K3 finalize_taps: reduce partials + bias + sigmoid -> per-(m,tap) corner
//                    offsets (int4) + folded bilinear weights (float4).
//  K4 dcn_fused    : BM=64 x BN=128 (grid 512 = 2 blocks/CU), 72 BK32 iters.
//                    A tile 64x256 bf16 in LDS with PADDED stride 264 (R6 had
//                    stride 256 -> 16-way bank conflicts, 8.3M cycles). Waves
//                    sample 2 rows/iter of next tap into regs, flush at tap
//                    boundary. B ping-pong 2x8KB. LDS 49KB. Amat eliminated.
// Workspace ~31 MB of 256 MiB.

#define CIN 256
#define COUT 256
#define HWS 4096      // H*W
#define MTOT 16384    // B*H*W
#define KTOT 2304     // CIN*9
#define SPLITK 8
#define AST 264       // Asm row stride (ushorts): 528B = 4 banks/row -> 2-way

typedef __attribute__((ext_vector_type(8))) short bf16x8;
typedef __attribute__((ext_vector_type(4))) float f32x4;

__device__ __forceinline__ unsigned short f2bf(float f) {
  unsigned int u = __float_as_uint(f);
  unsigned int r = (u + 0x7fffu + ((u >> 16) & 1u)) >> 16;
  return (unsigned short)r;
}
__device__ __forceinline__ float bf2f(unsigned short u) {
  return __uint_as_float(((unsigned int)u) << 16);
}

__device__ __forceinline__ void gload_lds16(const void* g, void* l) {
  __builtin_amdgcn_global_load_lds((const __attribute__((address_space(1))) void*)g,
                                   (__attribute__((address_space(3))) void*)l, 16, 0, 0);
}

// ---------------- K0: weight prep + zeropage ----------------
__global__ __launch_bounds__(256) void prep_weights(const float* __restrict__ w,
                                                    const float* __restrict__ pw,
                                                    unsigned short* __restrict__ WB,
                                                    unsigned short* __restrict__ PWs,
                                                    unsigned short* __restrict__ zerop) {
  int idx = blockIdx.x * 256 + threadIdx.x;
  if (idx < 512) {  // 8 KB zeropage
    *(uint4*)(zerop + idx * 8) = make_uint4(0, 0, 0, 0);
  }
  if (idx < KTOT * COUT) {
    int f = idx;
    int t_ = f & 7;
    int rest = f >> 3;
    int o = rest & 255;
    int kk = (rest >> 8) * 8 + t_;
    int k = kk >> 8, c = kk & 255;
    WB[f] = f2bf(w[o * KTOT + c * 9 + k]);
  } else {
    int f2 = idx - KTOT * COUT;   // < 2304*32
    int t_ = f2 & 7;
    int rest = f2 >> 3;
    int j = rest & 31;
    int kk = (rest >> 5) * 8 + t_;
    int k = kk >> 8, c = kk & 255;
    float v = (j < 27) ? pw[j * KTOT + c * 9 + k] : 0.0f;
    PWs[f2] = f2bf(v);
  }
}

// ---------------- K1: NCHW fp32 -> NHWC bf16 transpose ----------------
__global__ __launch_bounds__(256) void transpose_x(const float* __restrict__ x,
                                                   unsigned short* __restrict__ xt) {
  __shared__ float tile[32][33];
  int b = blockIdx.z;
  int hw0 = blockIdx.x * 32;
  int c0 = blockIdx.y * 32;
  int tx = threadIdx.x, ty = threadIdx.y;
  for (int i = ty; i < 32; i += 8)
    tile[i][tx] = x[(size_t)(b * CIN + c0 + i) * HWS + hw0 + tx];
  __syncthreads();
  for (int r = ty; r < 32; r += 8)
    xt[(size_t)(b * HWS + hw0 + r) * CIN + c0 + tx] = f2bf(tile[tx][r]);
}

// ---------------- K2: offset conv, split-K, BM=64, bf16-xt staging ----------------
__global__ __launch_bounds__(256) void offset_conv_sk(const unsigned short* __restrict__ xt,
                                                      const unsigned short* __restrict__ PWs,
                                                      const unsigned short* __restrict__ zerop,
                                                      float* __restrict__ Pbuf) {
  __shared__ unsigned short Al[64 * 32];   // 4 KB
  __shared__ unsigned short Bl[1024];      // 2 KB
  int tid = threadIdx.x;
  int lane = tid & 63, wv = tid >> 6;
  int mt = (blockIdx.x & 7) * 32 + (blockIdx.x >> 3);   // XCD swizzle
  int m0 = mt * 64;
  int s = blockIdx.y;
  int b = m0 >> 12;
  int hw0 = m0 & 4095;
  f32x4 acc[2] = {};

  for (int tt = 0; tt < 72 / SPLITK; ++tt) {
    int t = s * (72 / SPLITK) + tt;
    int k = t >> 3, c0 = (t & 7) * 32;
    int dyk = k / 3 - 1;
    int dxk = k % 3 - 1;
    __syncthreads();
    if (tid < 128)
      gload_lds16(PWs + (size_t)t * 1024 + tid * 8, &Bl[tid * 8]);
    {
      int r = tid >> 2;
      int hw = hw0 + r;
      int h = hw >> 6, wwp = hw & 63;
      int y = h + dyk, xx = wwp + dxk;
      bool valid = ((unsigned)y < 64u) && ((unsigned)xx < 64u);
      const unsigned short* src = valid
          ? xt + ((size_t)((b << 12) + (y << 6) + xx) << 8) + c0 + (tid & 3) * 8
          : zerop;
      gload_lds16(src, &Al[tid * 8]);
    }
    __syncthreads();
    int row = lane & 15, quad = lane >> 4;
    bf16x8 af = *(const bf16x8*)&Al[(wv * 16 + row) * 32 + quad * 8];
    for (int j = 0; j < 2; ++j) {
      bf16x8 bfr = *(const bf16x8*)&Bl[(quad * 32 + j * 16 + row) * 8];
      acc[j] = __builtin_amdgcn_mfma_f32_16x16x32_bf16(af, bfr, acc[j], 0, 0, 0);
    }
  }

  int row = lane & 15, quad = lane >> 4;
  for (int j = 0; j < 2; ++j) {
    int n = j * 16 + row;
    for (int r_ = 0; r_ < 4; ++r_) {
      int m = m0 + wv * 16 + quad * 4 + r_;
      Pbuf[((size_t)s * MTOT + m) * 32 + n] = acc[j][r_];
    }
  }
}

// ---------------- K3: finalize taps ----------------
__global__ __launch_bounds__(256) void finalize_taps(const float* __restrict__ Pbuf,
                                                     const float* __restrict__ p_bias,
                                                     int4* __restrict__ descI,
                                                     float4* __restrict__ descW) {
  int reg = blockIdx.x & 7;
  int tr = (blockIdx.x >> 3) * 256 + threadIdx.x;   // < 18432
  int ml = tr / 9;
  int k = tr - ml * 9;
  int m = reg * 2048 + ml;

  float dy = p_bias[2 * k];
  float dx = p_bias[2 * k + 1];
  float mv = p_bias[18 + k];
#pragma unroll
  for (int s = 0; s < SPLITK; ++s) {
    const float* p = Pbuf + ((size_t)s * MTOT + m) * 32;
    dy += p[2 * k];
    dx += p[2 * k + 1];
    mv += p[18 + k];
  }
  float mk = 1.0f / (1.0f + __expf(-mv));

  int hw = m & 4095, h = hw >> 6, ww = hw & 63;
  float py = (float)(h - 1 + k / 3) + dy;
  float px = (float)(ww - 1 + k % 3) + dx;
  float y0f = floorf(py), x0f = floorf(px);
  float ay = py - y0f, ax = px - x0f;
  int y0 = (int)y0f, x0 = (int)x0f;

  float w00 = (1.f - ay) * (1.f - ax) * mk;
  float w01 = (1.f - ay) * ax * mk;
  float w10 = ay * (1.f - ax) * mk;
  float w11 = ay * ax * mk;

  float vy0 = ((unsigned)y0 < 64u) ? 1.f : 0.f;
  float vy1 = ((unsigned)(y0 + 1) < 64u) ? 1.f : 0.f;
  float vx0 = ((unsigned)x0 < 64u) ? 1.f : 0.f;
  float vx1 = ((unsigned)(x0 + 1) < 64u) ? 1.f : 0.f;
  w00 *= vy0 * vx0; w01 *= vy0 * vx1; w10 *= vy1 * vx0; w11 *= vy1 * vx1;

  int yc0 = min(max(y0, 0), 63), yc1 = min(max(y0 + 1, 0), 63);
  int xc0 = min(max(x0, 0), 63), xc1 = min(max(x0 + 1, 0), 63);

  int di = m * 9 + k;
  descI[di] = make_int4((yc0 * 64 + xc0) * 256, (yc0 * 64 + xc1) * 256,
                        (yc1 * 64 + xc0) * 256, (yc1 * 64 + xc1) * 256);
  descW[di] = make_float4(w00, w01, w10, w11);
}

// ---------------- K4: fused sample + GEMM, BM=64 x BN=128, BK=32 ----------------
__global__ __launch_bounds__(256) void dcn_fused(const unsigned short* __restrict__ xt,
                                                 const unsigned short* __restrict__ WB,
                                                 const int4* __restrict__ descI,
                                                 const float4* __restrict__ descW,
                                                 const float* __restrict__ bias,
                                                 float* __restrict__ out) {
  __shared__ unsigned short Asm[64 * AST];       // 33 KB, padded A tile
  __shared__ unsigned short Bsm[2][4 * 128 * 8]; // 2 x 8 KB ping-pong
  int tid = threadIdx.x;
  int lane = tid & 63, wv = tid >> 6;
  int reg = blockIdx.x & 7;                      // XCD region
  int nhalf = (blockIdx.x >> 3) & 1;
  int mtile = blockIdx.x >> 4;                   // [0, 32)
  int m0 = reg * 2048 + mtile * 64;
  int n0 = nhalf * 128;
  int b = m0 >> 12, hw0 = m0 & 4095;
  const unsigned short* xtb = xt + (((size_t)b << 12) << 8);
  int row = lane & 15, quad = lane >> 4;
  f32x4 acc[4][2] = {};
  uint2 sreg[16];

  // stage one BK32 B chunk (8 KB) into buffer bufi
  auto stageB = [&](int it, int bufi) {
#pragma unroll
    for (int p = 0; p < 2; ++p) {
      int li = p * 256 + tid;
      int kb8 = li >> 7, col = li & 127;
      gload_lds16(WB + ((size_t)(it * 4 + kb8) * 256 + n0 + col) * 8, &Bsm[bufi][li * 8]);
    }
  };
  // sample one local row r of tap k -> 4 bf16 (channels 4*lane..+3)
  auto sampleRow = [&](int k, int r) -> uint2 {
    int di = (m0 + wv * 16 + r) * 9 + k;
    int4 o4 = descI[di];
    float4 w4 = descW[di];
    ushort4 t00 = *(const ushort4*)(xtb + o4.x + 4 * lane);
    ushort4 t01 = *(const ushort4*)(xtb + o4.y + 4 * lane);
    ushort4 t10 = *(const ushort4*)(xtb + o4.z + 4 * lane);
    ushort4 t11 = *(const ushort4*)(xtb + o4.w + 4 * lane);
    float r0 = w4.x * bf2f(t00.x) + w4.y * bf2f(t01.x) + w4.z * bf2f(t10.x) + w4.w * bf2f(t11.x);
    float r1 = w4.x * bf2f(t00.y) + w4.y * bf2f(t01.y) + w4.z * bf2f(t10.y) + w4.w * bf2f(t11.y);
    float r2 = w4.x * bf2f(t00.z) + w4.y * bf2f(t01.z) + w4.z * bf2f(t10.z) + w4.w * bf2f(t11.z);
    float r3 = w4.x * bf2f(t00.w) + w4.y * bf2f(t01.w) + w4.z * bf2f(t10.w) + w4.w * bf2f(t11.w);
    uint2 o;
    o.x = (unsigned)f2bf(r0) | ((unsigned)f2bf(r1) << 16);
    o.y = (unsigned)f2bf(r2) | ((unsigned)f2bf(r3) << 16);
    return o;
  };
  auto writeRow = [&](int r, uint2 v) {
    *(uint2*)&Asm[(wv * 16 + r) * AST + 4 * lane] = v;
  };

  // prologue: B chunk 0 + tap 0 A tile
  stageB(0, 0);
#pragma unroll
  for (int r = 0; r < 16; ++r) writeRow(r, sampleRow(0, r));
  __syncthreads();

  for (int k = 0; k < 9; ++k) {
#pragma unroll
    for (int q = 0; q < 8; ++q) {
      int it = k * 8 + q;
      int bufi = it & 1;
      if (it < 71) stageB(it + 1, bufi ^ 1);
      if (k < 8) {
        sreg[2 * q]     = sampleRow(k + 1, 2 * q);
        sreg[2 * q + 1] = sampleRow(k + 1, 2 * q + 1);
      }
      bf16x8 af[4], bfr[2];
#pragma unroll
      for (int i = 0; i < 4; ++i)
        af[i] = *(const bf16x8*)&Asm[(i * 16 + row) * AST + q * 32 + quad * 8];
#pragma unroll
      for (int j = 0; j < 2; ++j)
        bfr[j] = *(const bf16x8*)&Bsm[bufi][(quad * 128 + wv * 32 + j * 16 + row) * 8];
#pragma unroll
      for (int i = 0; i < 4; ++i)
#pragma unroll
        for (int j = 0; j < 2; ++j)
          acc[i][j] = __builtin_amdgcn_mfma_f32_16x16x32_bf16(af[i], bfr[j], acc[i][j], 0, 0, 0);
      __syncthreads();
    }
    if (k < 8) {   // flush tap k+1 A tile
#pragma unroll
      for (int r = 0; r < 16; ++r) writeRow(r, sreg[r]);
      __syncthreads();
    }
  }

  // epilogue: +bias, NCHW fp32
#pragma unroll
  for (int j = 0; j < 2; ++j) {
    int o = n0 + wv * 32 + j * 16 + row;
    float bo = bias[o];
#pragma unroll
    for (int i = 0; i < 4; ++i) {
      int hw = hw0 + i * 16 + quad * 4;
      float4 v;
      v.x = acc[i][j][0] + bo;
      v.y = acc[i][j][1] + bo;
      v.z = acc[i][j][2] + bo;
      v.w = acc[i][j][3] + bo;
      *(float4*)(out + (((size_t)(b * COUT + o)) << 12) + hw) = v;
    }
  }
}

// ---------------- launch ----------------
extern "C" void kernel_launch(void* const* d_in, const int* in_sizes, int n_in,
                              void* d_out, int out_size, void* d_ws, size_t ws_size,
                              hipStream_t stream) {
  const float* x        = (const float*)d_in[0];
  const float* weight   = (const float*)d_in[1];
  const float* bias     = (const float*)d_in[2];
  const float* p_weight = (const float*)d_in[3];
  const float* p_bias   = (const float*)d_in[4];
  float* out = (float*)d_out;
  char* ws = (char*)d_ws;

  // workspace layout (bytes); total ~31.2 MB
  const size_t OFF_XT   = 0;                          //  8,388,608  bf16 NHWC x
  const size_t OFF_WB   = OFF_XT + 8388608;           //  1,179,648  bf16
  const size_t OFF_PW   = OFF_WB + 1179648;           //    147,456  bf16
  const size_t OFF_P    = OFF_PW + 147456;            // 16,777,216  fp32 partials
  const size_t OFF_DI   = OFF_P + 16777216;           //  2,359,296  int4 desc
  const size_t OFF_DW   = OFF_DI + 2359296;           //  2,359,296  float4 desc
  const size_t OFF_ZP   = OFF_DW + 2359296;           //      8,192  zeropage

  unsigned short* xt   = (unsigned short*)(ws + OFF_XT);
  unsigned short* WB   = (unsigned short*)(ws + OFF_WB);
  unsigned short* PWs  = (unsigned short*)(ws + OFF_PW);
  float* Pbuf          = (float*)(ws + OFF_P);
  int4* descI          = (int4*)(ws + OFF_DI);
  float4* descW        = (float4*)(ws + OFF_DW);
  unsigned short* zerop = (unsigned short*)(ws + OFF_ZP);

  prep_weights<<<(KTOT * COUT + KTOT * 32) / 256, 256, 0, stream>>>(weight, p_weight, WB, PWs, zerop);
  transpose_x<<<dim3(128, 8, 4), dim3(32, 8), 0, stream>>>(x, xt);
  offset_conv_sk<<<dim3(MTOT / 64, SPLITK), 256, 0, stream>>>(xt, PWs, zerop, Pbuf);
  finalize_taps<<<(MTOT * 9) / 256, 256, 0, stream>>>(Pbuf, p_bias, descI, descW);
  dcn_fused<<<MTOT / 32, 256, 0, stream>>>(xt, WB, descI, descW, bias, out);
}

// Round 9
// 149.386 us; speedup vs baseline: 1.2523x; 1.2403x over previous
//
#include <hip/hip_runtime.h>
#include <stdint.h>

// DCNv2 forward, MI355X — R8: revert fusion (R6/R7 dead end), R5 pipeline with
// validated upgrades. 4 launches:
//  K0 prep_and_transpose : grid-split fused kernel.
//     - blocks [0,4096): x NCHW fp32 -> xt NHWC bf16 (32x32 LDS tiles)
//     - blocks [4096,..): W -> WB bf16 [kk/8][o][8]; p_weight -> PWs (N=32 pad);
//       zeropage zeroing (d_ws re-poisoned every launch).
//  K1 offset_conv_sk : split-K (S=8) implicit-im2col bf16 MFMA conv, BM=64,
//     XCD-swizzled; A staged via global_load_lds from bf16 xt (OOB->zeropage).
//  K2 sample9 : one wave per m, 9 taps; block inline-finalizes its 36 (m,tap)
//     descriptors (partials+bias+sigmoid -> corner offsets + folded weights)
//     into LDS, then bilinear-samples bf16 corners -> Amat bf16 [m][k*256+c].
//     XCD-swizzled to K1's half-batch regions.
//  K3 main_gemm : 128x64, BK=64 ping-pong LDS dbuf (R4-proven), +bias, NCHW fp32.
// Workspace ~102 MB of 256 MiB.

#define CIN 256
#define COUT 256
#define HWS 4096      // H*W
#define MTOT 16384    // B*H*W
#define KTOT 2304     // CIN*9
#define SPLITK 8

typedef __attribute__((ext_vector_type(8))) short bf16x8;
typedef __attribute__((ext_vector_type(4))) float f32x4;

__device__ __forceinline__ unsigned short f2bf(float f) {
  unsigned int u = __float_as_uint(f);
  unsigned int r = (u + 0x7fffu + ((u >> 16) & 1u)) >> 16;
  return (unsigned short)r;
}
__device__ __forceinline__ float bf2f(unsigned short u) {
  return __uint_as_float(((unsigned int)u) << 16);
}

__device__ __forceinline__ void gload_lds16(const void* g, void* l) {
  __builtin_amdgcn_global_load_lds((const __attribute__((address_space(1))) void*)g,
                                   (__attribute__((address_space(3))) void*)l, 16, 0, 0);
}

// ---------------- K0: fused transpose (NCHW fp32 -> NHWC bf16) + weight prep ----------------
__global__ __launch_bounds__(256) void prep_and_transpose(const float* __restrict__ x,
                                                          const float* __restrict__ w,
                                                          const float* __restrict__ pw,
                                                          unsigned short* __restrict__ xt,
                                                          unsigned short* __restrict__ WB,
                                                          unsigned short* __restrict__ PWs,
                                                          unsigned short* __restrict__ zerop) {
  __shared__ float tile[32][33];
  int bid = blockIdx.x;
  if (bid < 4096) {
    int b = bid >> 10;
    int rest = bid & 1023;
    int hw0 = (rest & 127) * 32;
    int c0 = ((rest >> 7) & 7) * 32;
    int tx = threadIdx.x & 31, ty = threadIdx.x >> 5;
    for (int i = ty; i < 32; i += 8)
      tile[i][tx] = x[(size_t)(b * CIN + c0 + i) * HWS + hw0 + tx];
    __syncthreads();
    for (int r = ty; r < 32; r += 8)
      xt[(size_t)(b * HWS + hw0 + r) * CIN + c0 + tx] = f2bf(tile[tx][r]);
  } else {
    int idx = (bid - 4096) * 256 + threadIdx.x;
    if (idx < 512)
      *(uint4*)(zerop + idx * 8) = make_uint4(0, 0, 0, 0);
    if (idx < KTOT * COUT) {
      int f = idx;
      int t_ = f & 7;
      int rest = f >> 3;
      int o = rest & 255;
      int kk = (rest >> 8) * 8 + t_;
      int k = kk >> 8, c = kk & 255;
      WB[f] = f2bf(w[o * KTOT + c * 9 + k]);
    } else {
      int f2 = idx - KTOT * COUT;   // < 2304*32
      int t_ = f2 & 7;
      int rest = f2 >> 3;
      int j = rest & 31;
      int kk = (rest >> 5) * 8 + t_;
      int k = kk >> 8, c = kk & 255;
      float v = (j < 27) ? pw[j * KTOT + c * 9 + k] : 0.0f;
      PWs[f2] = f2bf(v);
    }
  }
}

// ---------------- K1: offset conv, split-K, BM=64, bf16-xt global_load_lds staging ----------------
__global__ __launch_bounds__(256) void offset_conv_sk(const unsigned short* __restrict__ xt,
                                                      const unsigned short* __restrict__ PWs,
                                                      const unsigned short* __restrict__ zerop,
                                                      float* __restrict__ Pbuf) {
  __shared__ unsigned short Al[64 * 32];   // 4 KB
  __shared__ unsigned short Bl[1024];      // 2 KB
  int tid = threadIdx.x;
  int lane = tid & 63, wv = tid >> 6;
  int mt = (blockIdx.x & 7) * 32 + (blockIdx.x >> 3);   // XCD swizzle
  int m0 = mt * 64;
  int s = blockIdx.y;
  int b = m0 >> 12;
  int hw0 = m0 & 4095;
  f32x4 acc[2] = {};

  for (int tt = 0; tt < 72 / SPLITK; ++tt) {
    int t = s * (72 / SPLITK) + tt;
    int k = t >> 3, c0 = (t & 7) * 32;
    int dyk = k / 3 - 1;
    int dxk = k % 3 - 1;
    __syncthreads();
    if (tid < 128)
      gload_lds16(PWs + (size_t)t * 1024 + tid * 8, &Bl[tid * 8]);
    {
      int r = tid >> 2;
      int hw = hw0 + r;
      int h = hw >> 6, wwp = hw & 63;
      int y = h + dyk, xx = wwp + dxk;
      bool valid = ((unsigned)y < 64u) && ((unsigned)xx < 64u);
      const unsigned short* src = valid
          ? xt + ((size_t)((b << 12) + (y << 6) + xx) << 8) + c0 + (tid & 3) * 8
          : zerop;
      gload_lds16(src, &Al[tid * 8]);
    }
    __syncthreads();
    int row = lane & 15, quad = lane >> 4;
    bf16x8 af = *(const bf16x8*)&Al[(wv * 16 + row) * 32 + quad * 8];
    for (int j = 0; j < 2; ++j) {
      bf16x8 bfr = *(const bf16x8*)&Bl[(quad * 32 + j * 16 + row) * 8];
      acc[j] = __builtin_amdgcn_mfma_f32_16x16x32_bf16(af, bfr, acc[j], 0, 0, 0);
    }
  }

  int row = lane & 15, quad = lane >> 4;
  for (int j = 0; j < 2; ++j) {
    int n = j * 16 + row;
    for (int r_ = 0; r_ < 4; ++r_) {
      int m = m0 + wv * 16 + quad * 4 + r_;
      Pbuf[((size_t)s * MTOT + m) * 32 + n] = acc[j][r_];
    }
  }
}

// ---------------- K2: sample9 with inline tap finalize ----------------
// Block = 4 waves = 4 consecutive m. Threads 0..35 build the 4x9 descriptors
// (split-K reduce + bias + sigmoid + clamp/fold) into LDS; one barrier; each
// wave samples its m's 9 taps (bf16 corners) -> Amat.
__global__ __launch_bounds__(256) void sample9(const unsigned short* __restrict__ xt,
                                               const float* __restrict__ Pbuf,
                                               const float* __restrict__ p_bias,
                                               unsigned short* __restrict__ A) {
  __shared__ int4 dI[4][9];
  __shared__ float4 dW[4][9];
  int tid = threadIdx.x;
  int reg = blockIdx.x & 7;                     // XCD region (matches K1)
  int mb = reg * 2048 + (blockIdx.x >> 3) * 4;  // base m of this block

  if (tid < 36) {
    int lm = tid / 9, k = tid - lm * 9;
    int m = mb + lm;
    float dy = p_bias[2 * k];
    float dx = p_bias[2 * k + 1];
    float mv = p_bias[18 + k];
#pragma unroll
    for (int s = 0; s < SPLITK; ++s) {
      const float* p = Pbuf + ((size_t)s * MTOT + m) * 32;
      dy += p[2 * k];
      dx += p[2 * k + 1];
      mv += p[18 + k];
    }
    float mk = 1.0f / (1.0f + __expf(-mv));

    int hw = m & 4095, h = hw >> 6, ww = hw & 63;
    float py = (float)(h - 1 + k / 3) + dy;
    float px = (float)(ww - 1 + k % 3) + dx;
    float y0f = floorf(py), x0f = floorf(px);
    float ay = py - y0f, ax = px - x0f;
    int y0 = (int)y0f, x0 = (int)x0f;

    float w00 = (1.f - ay) * (1.f - ax) * mk;
    float w01 = (1.f - ay) * ax * mk;
    float w10 = ay * (1.f - ax) * mk;
    float w11 = ay * ax * mk;

    float vy0 = ((unsigned)y0 < 64u) ? 1.f : 0.f;
    float vy1 = ((unsigned)(y0 + 1) < 64u) ? 1.f : 0.f;
    float vx0 = ((unsigned)x0 < 64u) ? 1.f : 0.f;
    float vx1 = ((unsigned)(x0 + 1) < 64u) ? 1.f : 0.f;
    w00 *= vy0 * vx0; w01 *= vy0 * vx1; w10 *= vy1 * vx0; w11 *= vy1 * vx1;

    int yc0 = min(max(y0, 0), 63), yc1 = min(max(y0 + 1, 0), 63);
    int xc0 = min(max(x0, 0), 63), xc1 = min(max(x0 + 1, 0), 63);

    dI[lm][k] = make_int4((yc0 * 64 + xc0) * 256, (yc0 * 64 + xc1) * 256,
                          (yc1 * 64 + xc0) * 256, (yc1 * 64 + xc1) * 256);
    dW[lm][k] = make_float4(w00, w01, w10, w11);
  }
  __syncthreads();

  int wv = tid >> 6, lane = tid & 63;
  int m = mb + wv;
  int b = m >> 12;
  const unsigned short* xtb = xt + (((size_t)b << 12) << 8);
  unsigned short* outp = A + (size_t)m * KTOT + lane * 4;

#pragma unroll
  for (int k = 0; k < 9; ++k) {
    int4 o4 = dI[wv][k];       // LDS broadcast (same addr across wave) — free
    float4 w4 = dW[wv][k];
    ushort4 t00 = *(const ushort4*)(xtb + o4.x + 4 * lane);
    ushort4 t01 = *(const ushort4*)(xtb + o4.y + 4 * lane);
    ushort4 t10 = *(const ushort4*)(xtb + o4.z + 4 * lane);
    ushort4 t11 = *(const ushort4*)(xtb + o4.w + 4 * lane);
    float r0 = w4.x * bf2f(t00.x) + w4.y * bf2f(t01.x) + w4.z * bf2f(t10.x) + w4.w * bf2f(t11.x);
    float r1 = w4.x * bf2f(t00.y) + w4.y * bf2f(t01.y) + w4.z * bf2f(t10.y) + w4.w * bf2f(t11.y);
    float r2 = w4.x * bf2f(t00.z) + w4.y * bf2f(t01.z) + w4.z * bf2f(t10.z) + w4.w * bf2f(t11.z);
    float r3 = w4.x * bf2f(t00.w) + w4.y * bf2f(t01.w) + w4.z * bf2f(t10.w) + w4.w * bf2f(t11.w);
    ushort4 o;
    o.x = f2bf(r0); o.y = f2bf(r1); o.z = f2bf(r2); o.w = f2bf(r3);
    *(ushort4*)(outp + k * 256) = o;
  }
}

// ---------------- K3: main GEMM 128x64, BK=64 (2x32), ping-pong dbuf ----------------
__global__ __launch_bounds__(256) void main_gemm(const unsigned short* __restrict__ Amat,
                                                 const unsigned short* __restrict__ WB,
                                                 const float* __restrict__ bias,
                                                 float* __restrict__ out) {
  __shared__ unsigned short Al[2][2][128 * 32];  // 32 KB
  __shared__ unsigned short Bl[2][8 * 64 * 8];   // 16 KB
  int tid = threadIdx.x;
  int lane = tid & 63, wv = tid >> 6;
  int m0 = blockIdx.x * 128;
  int n0 = blockIdx.y * 64;
  int wm = wv * 32;
  f32x4 acc[2][4] = {};

  auto stage = [&](int t, int buf) {
#pragma unroll
    for (int p = 0; p < 4; ++p) {
      int li = p * 256 + tid;
      int ks = li >> 9;
      int li2 = li & 511;
      int row = li2 >> 2, ch = li2 & 3;
      const unsigned short* src = Amat + (size_t)(m0 + row) * KTOT + t * 64 + ks * 32 + ch * 8;
      gload_lds16(src, &Al[buf][ks][li2 * 8]);
    }
#pragma unroll
    for (int p = 0; p < 2; ++p) {
      int li = p * 256 + tid;
      int kb8 = li >> 6, col = li & 63;
      const unsigned short* src = WB + ((size_t)(t * 8 + kb8) * 256 + n0 + col) * 8;
      gload_lds16(src, &Bl[buf][li * 8]);
    }
  };

  stage(0, 0);
  __syncthreads();

  int row = lane & 15, quad = lane >> 4;
  for (int t = 0; t < 36; ++t) {
    int cur = t & 1;
    if (t < 35) stage(t + 1, cur ^ 1);
#pragma unroll
    for (int ks = 0; ks < 2; ++ks) {
      bf16x8 af[2], bfr[4];
#pragma unroll
      for (int i = 0; i < 2; ++i)
        af[i] = *(const bf16x8*)&Al[cur][ks][(wm + i * 16 + row) * 32 + quad * 8];
#pragma unroll
      for (int j = 0; j < 4; ++j)
        bfr[j] = *(const bf16x8*)&Bl[cur][((ks * 4 + quad) * 64 + j * 16 + row) * 8];
#pragma unroll
      for (int i = 0; i < 2; ++i)
#pragma unroll
        for (int j = 0; j < 4; ++j)
          acc[i][j] = __builtin_amdgcn_mfma_f32_16x16x32_bf16(af[i], bfr[j], acc[i][j], 0, 0, 0);
    }
    __syncthreads();
  }

  int b = m0 >> 12, hw0 = m0 & 4095;
  for (int j = 0; j < 4; ++j) {
    int o = n0 + j * 16 + row;
    float bo = bias[o];
    for (int i = 0; i < 2; ++i) {
      int hw = hw0 + wm + i * 16 + quad * 4;
      float4 v;
      v.x = acc[i][j][0] + bo;
      v.y = acc[i][j][1] + bo;
      v.z = acc[i][j][2] + bo;
      v.w = acc[i][j][3] + bo;
      *(float4*)(out + (((size_t)(b * COUT + o)) << 12) + hw) = v;
    }
  }
}

// ---------------- launch ----------------
extern "C" void kernel_launch(void* const* d_in, const int* in_sizes, int n_in,
                              void* d_out, int out_size, void* d_ws, size_t ws_size,
                              hipStream_t stream) {
  const float* x        = (const float*)d_in[0];
  const float* weight   = (const float*)d_in[1];
  const float* bias     = (const float*)d_in[2];
  const float* p_weight = (const float*)d_in[3];
  const float* p_bias   = (const float*)d_in[4];
  float* out = (float*)d_out;
  char* ws = (char*)d_ws;

  // workspace layout (bytes); total ~102 MB of 256 MiB
  const size_t OFF_XT   = 0;                          //  8,388,608  bf16 NHWC x
  const size_t OFF_WB   = OFF_XT + 8388608;           //  1,179,648  bf16
  const size_t OFF_PW   = OFF_WB + 1179648;           //    147,456  bf16
  const size_t OFF_P    = OFF_PW + 147456;            // 16,777,216  fp32 partials
  const size_t OFF_ZP   = OFF_P + 16777216;           //      8,192  zeropage
  const size_t OFF_A    = OFF_ZP + 8192;              // 75,497,472  bf16 Amat

  unsigned short* xt    = (unsigned short*)(ws + OFF_XT);
  unsigned short* WB    = (unsigned short*)(ws + OFF_WB);
  unsigned short* PWs   = (unsigned short*)(ws + OFF_PW);
  float* Pbuf           = (float*)(ws + OFF_P);
  unsigned short* zerop = (unsigned short*)(ws + OFF_ZP);
  unsigned short* Amat  = (unsigned short*)(ws + OFF_A);

  prep_and_transpose<<<4096 + 2592, 256, 0, stream>>>(x, weight, p_weight, xt, WB, PWs, zerop);
  offset_conv_sk<<<dim3(MTOT / 64, SPLITK), 256, 0, stream>>>(xt, PWs, zerop, Pbuf);
  sample9<<<MTOT / 4, 256, 0, stream>>>(xt, Pbuf, p_bias, Amat);
  main_gemm<<<dim3(MTOT / 128, COUT / 64), 256, 0, stream>>>(Amat, WB, bias, out);
}